// Round 6
// baseline (405.676 us; speedup 1.0000x reference)
//
#include <hip/hip_runtime.h>

// context_window: out[b, f*CTX + c, t] = x[b, f, t + c - P] (zero-padded)
// B=32, F=80, T=3000, l=r=5 -> P=5, lag=0, CTX=11
//
// R6: INSTRUMENTATION round. The bench window hides the kernel behind a
// ~220 us harness poison fill (top-5 is all fills; kernel < 218 us, est.
// ~130 us = 2.8 TB/s vs the fill's proven 6 TB/s). To get the kernel's own
// rocprof counters we run the idempotent stage+emit TWICE in one dispatch
// (~260 us -> enters top-5). Diagnostic: FETCH_SIZE ~60 MB => stores clean;
// FETCH_SIZE ~700 MB => read-for-allocate on store misses (explains the 2x).

#define BB   32
#define FF   80
#define TT   3000
#define PW   5          // P = max(l, r)
#define CTX  11         // l + r + 1
#define T4   (TT / 4)   // 750 float4 per row
#define NTHREADS 256
#define NJJ  3          // ceil(750/256) j-chunks per thread
#define REPS 2          // instrumentation: double the work to surface in rocprof

typedef float vf4 __attribute__((ext_vector_type(4)));

__global__ __launch_bounds__(NTHREADS) void context_window_43233140801616_kernel(
    const float* __restrict__ x, float* __restrict__ out) {
    __shared__ vf4 s4buf[(TT + 2 * PW + 2) / 4 + 1];   // 754 float4 = 12.06 KB
    float* s = (float*)s4buf;
    const vf4* s4 = (const vf4*)s;

    const int row = blockIdx.x;       // 0 .. B*F-1 ; row = b*F + f
    const int tid = threadIdx.x;

    for (int rep = 0; rep < REPS; ++rep) {
        // ---- Stage padded row into LDS ----
        const vf4* xrow = (const vf4*)(x + (size_t)row * TT);
        for (int j = tid; j < T4; j += NTHREADS) {
            vf4 v = xrow[j];
            int base = PW + 4 * j;
            s[base + 0] = v.x;
            s[base + 1] = v.y;
            s[base + 2] = v.z;
            s[base + 3] = v.w;
        }
        if (tid < PW) {
            s[tid] = 0.0f;                       // left pad  xp[0..4]
            s[TT + PW + tid] = 0.0f;             // right pad xp[3005..3009]
        }
        if (tid < 6) {
            s[TT + 2 * PW + tid] = 0.0f;         // overread guard
        }
        __syncthreads();

        // ---- Load this thread's windows into registers ----
        float w[NJJ][16];
#pragma unroll
        for (int jj = 0; jj < NJJ; ++jj) {
            int j = tid + jj * NTHREADS;
            if (j < T4) {
                vf4 a = s4[j];
                vf4 b = s4[j + 1];
                vf4 c4 = s4[j + 2];
                vf4 d = s4[j + 3];
                w[jj][0] = a.x;  w[jj][1] = a.y;  w[jj][2] = a.z;  w[jj][3] = a.w;
                w[jj][4] = b.x;  w[jj][5] = b.y;  w[jj][6] = b.z;  w[jj][7] = b.w;
                w[jj][8] = c4.x; w[jj][9] = c4.y; w[jj][10] = c4.z; w[jj][11] = c4.w;
                w[jj][12] = d.x; w[jj][13] = d.y; w[jj][14] = d.z; w[jj][15] = d.w;
            }
        }

        // ---- Emit, c-major: block writes its 132-KB slab front-to-back ----
        float* orow = out + (size_t)row * CTX * TT;
#pragma unroll
        for (int c = 0; c < CTX; ++c) {
            vf4* oc = (vf4*)(orow + c * TT);
#pragma unroll
            for (int jj = 0; jj < NJJ; ++jj) {
                int j = tid + jj * NTHREADS;
                if (j < T4) {
                    vf4 v = {w[jj][c], w[jj][c + 1], w[jj][c + 2], w[jj][c + 3]};
                    oc[j] = v;
                }
            }
        }
        __syncthreads();   // keep reps non-overlapping in LDS
    }
}

extern "C" void kernel_launch(void* const* d_in, const int* in_sizes, int n_in,
                              void* d_out, int out_size, void* d_ws, size_t ws_size,
                              hipStream_t stream) {
    const float* x = (const float*)d_in[0];
    // d_in[1] = left_frames(=5), d_in[2] = right_frames(=5): fixed by
    // setup_inputs, baked into PW/CTX constants above.
    float* out = (float*)d_out;
    context_window_43233140801616_kernel<<<BB * FF, NTHREADS, 0, stream>>>(x, out);
}

// Round 7
// 364.167 us; speedup vs baseline: 1.1140x; 1.1140x over previous
//
#include <hip/hip_runtime.h>

// context_window: out[b, f*CTX + c, t] = x[b, f, t + c - P] (zero-padded)
// B=32, F=80, T=3000, l=r=5 -> P=5, lag=0, CTX=11
//
// FINAL (R5 structure, instrumentation reverted). Evidence from R6 REPS=2
// probe: marginal cost of one full stage+emit pass ~= 44 us — at the
// 338 MB-write + 31 MB-read HBM floor (~59 us @6.3 TB/s, with the 256 MiB
// L3 absorbing part of the drain). The remaining ~320 us of the bench
// window is fixed harness work (1.35 GB 0xAA poison fill ~220 us + input
// restore + launch gaps) and is not addressable from the kernel.
//
// Structure: block per (b,f) row. Stage padded row in LDS (vectorized,
// conflict-free). Each thread loads its three 16-float windows via aligned
// ds_read_b128 into registers, then the block writes its 132-KB output slab
// strictly front-to-back in c-major order (DRAM/L2-friendly sequential
// stream — worth ~12% over c-inner interleaved, R4->R5).

#define BB   32
#define FF   80
#define TT   3000
#define PW   5          // P = max(l, r)
#define CTX  11         // l + r + 1
#define T4   (TT / 4)   // 750 float4 per row
#define NTHREADS 256
#define NJJ  3          // ceil(750/256) j-chunks per thread

typedef float vf4 __attribute__((ext_vector_type(4)));

__global__ __launch_bounds__(NTHREADS) void context_window_43233140801616_kernel(
    const float* __restrict__ x, float* __restrict__ out) {
    // s[m] = xp[m]; tail so s4[j+3] for j=749 stays in-bounds.
    __shared__ vf4 s4buf[(TT + 2 * PW + 2) / 4 + 1];   // 754 float4 = 12.06 KB
    float* s = (float*)s4buf;
    const vf4* s4 = (const vf4*)s;

    const int row = blockIdx.x;       // 0 .. B*F-1 ; row = b*F + f
    const int tid = threadIdx.x;

    // ---- Stage padded row into LDS ----
    const vf4* xrow = (const vf4*)(x + (size_t)row * TT);
    for (int j = tid; j < T4; j += NTHREADS) {
        vf4 v = xrow[j];
        int base = PW + 4 * j;
        s[base + 0] = v.x;
        s[base + 1] = v.y;
        s[base + 2] = v.z;
        s[base + 3] = v.w;
    }
    if (tid < PW) {
        s[tid] = 0.0f;                       // left pad  xp[0..4]
        s[TT + PW + tid] = 0.0f;             // right pad xp[3005..3009]
    }
    if (tid < 6) {
        s[TT + 2 * PW + tid] = 0.0f;         // overread guard
    }
    __syncthreads();

    // ---- Load this thread's windows into registers (once) ----
    // Window jj covers xp[4*j .. 4*j+15] for j = tid + jj*256.
    float w[NJJ][16];
#pragma unroll
    for (int jj = 0; jj < NJJ; ++jj) {
        int j = tid + jj * NTHREADS;
        if (j < T4) {
            vf4 a = s4[j];
            vf4 b = s4[j + 1];
            vf4 c4 = s4[j + 2];
            vf4 d = s4[j + 3];
            w[jj][0] = a.x;  w[jj][1] = a.y;  w[jj][2] = a.z;  w[jj][3] = a.w;
            w[jj][4] = b.x;  w[jj][5] = b.y;  w[jj][6] = b.z;  w[jj][7] = b.w;
            w[jj][8] = c4.x; w[jj][9] = c4.y; w[jj][10] = c4.z; w[jj][11] = c4.w;
            w[jj][12] = d.x; w[jj][13] = d.y; w[jj][14] = d.z; w[jj][15] = d.w;
        }
    }

    // ---- Emit, c-major: block writes its 132-KB slab front-to-back ----
    float* orow = out + (size_t)row * CTX * TT;
#pragma unroll
    for (int c = 0; c < CTX; ++c) {
        vf4* oc = (vf4*)(orow + c * TT);
#pragma unroll
        for (int jj = 0; jj < NJJ; ++jj) {
            int j = tid + jj * NTHREADS;
            if (j < T4) {
                vf4 v = {w[jj][c], w[jj][c + 1], w[jj][c + 2], w[jj][c + 3]};
                oc[j] = v;
            }
        }
    }
}

extern "C" void kernel_launch(void* const* d_in, const int* in_sizes, int n_in,
                              void* d_out, int out_size, void* d_ws, size_t ws_size,
                              hipStream_t stream) {
    const float* x = (const float*)d_in[0];
    // d_in[1] = left_frames(=5), d_in[2] = right_frames(=5): fixed by
    // setup_inputs, baked into PW/CTX constants above.
    float* out = (float*)d_out;
    context_window_43233140801616_kernel<<<BB * FF, NTHREADS, 0, stream>>>(x, out);
}